// Round 1
// baseline (188.568 us; speedup 1.0000x reference)
//
#include <hip/hip_runtime.h>

// Problem constants
#define N_TOK 8192
#define N_EXP 8
#define DIM   2048
#define HID   2048

typedef __attribute__((ext_vector_type(8))) short short8;
typedef __attribute__((ext_vector_type(4))) float f32x4;
typedef __attribute__((ext_vector_type(4))) unsigned short ushort4v;

__device__ inline unsigned short f2bf(float f) {
  unsigned int u = __builtin_bit_cast(unsigned int, f);
  unsigned int r = u + 0x7FFFu + ((u >> 16) & 1u);   // round-to-nearest-even
  return (unsigned short)(r >> 16);
}

// ---------------------------------------------------------------------------
// Kernel 1: stable counting sort by expert id. One block, 256 threads.
// perm[p] = source row for sorted position p; offs[e..e+1] = segment bounds.
// ---------------------------------------------------------------------------
__global__ __launch_bounds__(256) void sort_experts(const int* __restrict__ idx,
                                                    int* __restrict__ perm,
                                                    int* __restrict__ offs) {
  __shared__ int cnt[256][8];
  __shared__ int base[8];
  const int t = threadIdx.x;
  int local[8] = {0,0,0,0,0,0,0,0};
  const int r0 = t * 32;
  for (int i = 0; i < 32; ++i) {
    int e = idx[r0 + i] & 7;
    ++local[e];
  }
#pragma unroll
  for (int e = 0; e < 8; ++e) cnt[t][e] = local[e];
  __syncthreads();
  if (t < 8) {
    int s = 0;
    for (int i = 0; i < 256; ++i) { int v = cnt[i][t]; cnt[i][t] = s; s += v; }
    base[t] = s;  // total count for expert t
  }
  __syncthreads();
  if (t == 0) {
    int s = 0;
    for (int e = 0; e < 8; ++e) { int v = base[e]; offs[e] = s; base[e] = s; s += v; }
    offs[8] = s;
  }
  __syncthreads();
  int pos[8];
#pragma unroll
  for (int e = 0; e < 8; ++e) pos[e] = base[e] + cnt[t][e];
  for (int i = 0; i < 32; ++i) {
    int r = r0 + i;
    int e = idx[r] & 7;
    perm[pos[e]++] = r;
  }
}

// ---------------------------------------------------------------------------
// Kernel 2: gather rows into sorted order + fp32 -> bf16.
// grid = N_TOK * (DIM/8) / 256 = 8192 blocks. Each thread: 8 elements.
// ---------------------------------------------------------------------------
__global__ __launch_bounds__(256) void gather_convert_x(const float* __restrict__ x,
                                                        const int* __restrict__ perm,
                                                        unsigned short* __restrict__ xs) {
  int gid = blockIdx.x * 256 + threadIdx.x;
  int p = gid >> 8;          // sorted position (DIM/8 = 256 chunks per row)
  int c = gid & 255;
  int src = perm[p];
  const float* sp = x + (size_t)src * DIM + c * 8;
  float4 a = *(const float4*)sp;
  float4 b = *(const float4*)(sp + 4);
  short8 o;
  o[0] = (short)f2bf(a.x); o[1] = (short)f2bf(a.y);
  o[2] = (short)f2bf(a.z); o[3] = (short)f2bf(a.w);
  o[4] = (short)f2bf(b.x); o[5] = (short)f2bf(b.y);
  o[6] = (short)f2bf(b.z); o[7] = (short)f2bf(b.w);
  *(short8*)(xs + (size_t)p * DIM + c * 8) = o;
}

// ---------------------------------------------------------------------------
// Kernel 3: W[e][d][h] fp32 -> Wt[e][h][d] bf16 (LDS-tiled transpose).
// grid = (HID/64, DIM/64, N_EXP), 256 threads, 64x64 tile.
// ---------------------------------------------------------------------------
__global__ __launch_bounds__(256) void transpose_convert_w(const float* __restrict__ W,
                                                           unsigned short* __restrict__ Wt) {
  __shared__ unsigned short tile[64][68];   // pad 68: 8B-aligned rows
  const int e = blockIdx.z;
  const int d0 = blockIdx.y * 64;
  const int h0 = blockIdx.x * 64;
  const int t = threadIdx.x;
  const int cr = t & 15;    // column group (4 elems)
  const int rr = t >> 4;    // row within 16-row pass
  const float* Wp = W + ((size_t)e * DIM + d0) * HID + h0;
#pragma unroll
  for (int i = 0; i < 4; ++i) {
    int d = rr + i * 16;
    float4 v = *(const float4*)(Wp + (size_t)d * HID + cr * 4);
    ushort4v o;
    o[0] = f2bf(v.x); o[1] = f2bf(v.y); o[2] = f2bf(v.z); o[3] = f2bf(v.w);
    *(ushort4v*)&tile[d][cr * 4] = o;
  }
  __syncthreads();
  unsigned short* op = Wt + ((size_t)e * HID + h0) * DIM + d0;
#pragma unroll
  for (int i = 0; i < 4; ++i) {
    int h = rr + i * 16;
    ushort4v o;
    o[0] = tile[cr * 4 + 0][h];
    o[1] = tile[cr * 4 + 1][h];
    o[2] = tile[cr * 4 + 2][h];
    o[3] = tile[cr * 4 + 3][h];
    *(ushort4v*)(op + (size_t)h * DIM + cr * 4) = o;
  }
}

// ---------------------------------------------------------------------------
// Kernel 4: grouped GEMM (m97 structure): 128x128 tile, BK=32, 4 waves,
// global_load_lds staging, mfma_f32_16x16x32_bf16, fused bias+relu.
// A = xs (sorted, [p][d]), B^T = Wt[e] ([h][d]) -> C[p][h].
// ---------------------------------------------------------------------------
#define BM 128
#define BN 128
#define BK 32

__global__ __launch_bounds__(256) void grouped_gemm(const unsigned short* __restrict__ xs,
                                                    const unsigned short* __restrict__ Wt,
                                                    const float* __restrict__ bias,
                                                    const int* __restrict__ offs,
                                                    float* __restrict__ out) {
  const int e   = blockIdx.z;
  const int off = offs[e];
  const int cnt = offs[e + 1] - off;
  const int mt  = blockIdx.y;
  if (mt * BM >= cnt) return;
  const int n0 = blockIdx.x * BN;

  __shared__ __align__(16) unsigned short As[BM * BK];
  __shared__ __align__(16) unsigned short Bs[BN * BK];

  const int t    = threadIdx.x;
  const int wid  = t >> 6;
  const int lane = t & 63;
  const int wr   = wid >> 1, wc = wid & 1;
  const int l15  = lane & 15;
  const int l4   = lane >> 4;

  f32x4 acc[4][4] = {};

  // staging source addresses (element offsets at k0 = 0)
  size_t srcA[2], srcB[2];
  const size_t WtE = (size_t)e * DIM * HID;
#pragma unroll
  for (int c = 0; c < 2; ++c) {
    int lin = c * 256 + t;
    int r = lin >> 2, kq = lin & 3;     // 4 lanes of 16B per 64B row
    int p = off + mt * BM + r;
    if (p > N_TOK - 1) p = N_TOK - 1;   // clamp for memory safety (masked at store)
    srcA[c] = (size_t)p * DIM + kq * 8;
    srcB[c] = WtE + (size_t)(n0 + r) * DIM + kq * 8;
  }

  for (int k0 = 0; k0 < DIM; k0 += BK) {
#pragma unroll
    for (int c = 0; c < 2; ++c) {
      __builtin_amdgcn_global_load_lds(
          (const __attribute__((address_space(1))) void*)(xs + srcA[c] + k0),
          (__attribute__((address_space(3))) void*)(As + c * 2048 + t * 8), 16, 0, 0);
      __builtin_amdgcn_global_load_lds(
          (const __attribute__((address_space(1))) void*)(Wt + srcB[c] + k0),
          (__attribute__((address_space(3))) void*)(Bs + c * 2048 + t * 8), 16, 0, 0);
    }
    __syncthreads();

    short8 af[4], bf[4];
#pragma unroll
    for (int m = 0; m < 4; ++m) {
      int row = wr * 64 + m * 16 + l15;
      af[m] = *(const short8*)(As + row * BK + l4 * 8);
    }
#pragma unroll
    for (int n = 0; n < 4; ++n) {
      int row = wc * 64 + n * 16 + l15;
      bf[n] = *(const short8*)(Bs + row * BK + l4 * 8);
    }
#pragma unroll
    for (int m = 0; m < 4; ++m)
#pragma unroll
      for (int n = 0; n < 4; ++n)
        acc[m][n] = __builtin_amdgcn_mfma_f32_16x16x32_bf16(af[m], bf[n], acc[m][n], 0, 0, 0);
    __syncthreads();
  }

  // epilogue: bias + relu, masked tail rows, contiguous sorted-output writes
#pragma unroll
  for (int n = 0; n < 4; ++n) {
    int col = n0 + wc * 64 + n * 16 + l15;
    float bv = bias[e * HID + col];
#pragma unroll
    for (int m = 0; m < 4; ++m) {
#pragma unroll
      for (int q = 0; q < 4; ++q) {
        int rl = wr * 64 + m * 16 + l4 * 4 + q;
        if (mt * BM + rl < cnt) {
          float v = acc[m][n][q] + bv;
          out[(size_t)(off + mt * BM + rl) * HID + col] = v > 0.f ? v : 0.f;
        }
      }
    }
  }
}

// ---------------------------------------------------------------------------
extern "C" void kernel_launch(void* const* d_in, const int* in_sizes, int n_in,
                              void* d_out, int out_size, void* d_ws, size_t ws_size,
                              hipStream_t stream) {
  const float* x   = (const float*)d_in[0];
  const int*   idx = (const int*)d_in[1];
  const float* W   = (const float*)d_in[2];
  const float* b   = (const float*)d_in[3];
  float* out = (float*)d_out;

  char* ws = (char*)d_ws;
  unsigned short* xs = (unsigned short*)ws;                                   // 32 MB
  unsigned short* Wt = (unsigned short*)(ws + (size_t)N_TOK * DIM * 2);       // 64 MB
  int* perm = (int*)(ws + (size_t)N_TOK * DIM * 2 + (size_t)N_EXP * DIM * HID * 2);
  int* offs = perm + N_TOK;

  sort_experts<<<1, 256, 0, stream>>>(idx, perm, offs);
  gather_convert_x<<<N_TOK * (DIM / 8) / 256, 256, 0, stream>>>(x, perm, xs);
  transpose_convert_w<<<dim3(HID / 64, DIM / 64, N_EXP), 256, 0, stream>>>(W, Wt);
  grouped_gemm<<<dim3(HID / BN, N_TOK / BM, N_EXP), 256, 0, stream>>>(xs, Wt, b, offs, out);
}